// Round 10
// baseline (3688.497 us; speedup 1.0000x reference)
//
#include <hip/hip_runtime.h>
#include <hip/hip_bf16.h>
#include <stdint.h>

#define EPSV 1e-5f

typedef int i32x4 __attribute__((ext_vector_type(4)));

__device__ __forceinline__ void gload_lds16(const void* g, void* l) {
    __builtin_amdgcn_global_load_lds(
        (const __attribute__((address_space(1))) uint32_t*)g,
        (__attribute__((address_space(3))) uint32_t*)l, 16, 0, 0);
}

// ---------------------------------------------------------------------------
// Block reduction helpers (256 threads = 4 waves of 64)
// ---------------------------------------------------------------------------
__device__ __forceinline__ float block_sum256(float v, float* red) {
#pragma unroll
    for (int off = 32; off; off >>= 1) v += __shfl_down(v, off);
    int lane = threadIdx.x & 63, w = threadIdx.x >> 6;
    __syncthreads();
    if (lane == 0) red[w] = v;
    __syncthreads();
    return red[0] + red[1] + red[2] + red[3];
}

// ---------------------------------------------------------------------------
// ln_quant: row LayerNorm -> dual-term i8 quantized output + per-row scale.
// Layout: Aq[row][kt64][ a1 bytes 0..63 | a2 bytes 64..127 ], row stride 2K B.
// y = LN(x)*g + b;  y ~= sA[row] * (a1 + a2/128),  |err| <= rowmax * 2^-15.
// ---------------------------------------------------------------------------
__global__ __launch_bounds__(256)
void ln_quant(const float* __restrict__ X, const float* __restrict__ g,
              const float* __restrict__ b, uint8_t* __restrict__ Aq,
              float* __restrict__ sA, int D) {
    __shared__ float red[4];
    __shared__ float ybuf[1024];
    int row = blockIdx.x;
    const float* x = X + (size_t)row * D;
    int tid = threadIdx.x;
    int nvec = D >> 2;

    float s = 0.f, sq = 0.f;
    for (int i = tid; i < nvec; i += 256) {
        float4 v = ((const float4*)x)[i];
        s += v.x + v.y + v.z + v.w;
        sq += v.x * v.x + v.y * v.y + v.z * v.z + v.w * v.w;
    }
    float ts = block_sum256(s, red);
    float tq = block_sum256(sq, red);
    float invD = 1.f / (float)D;
    float mu = ts * invD;
    float rstd = rsqrtf(tq * invD - mu * mu + EPSV);

    float mx = 0.f;
    for (int i = tid; i < nvec; i += 256) {
        float4 v = ((const float4*)x)[i];
        float4 gv = ((const float4*)g)[i];
        float4 bv = ((const float4*)b)[i];
        float4 y;
        y.x = (v.x - mu) * rstd * gv.x + bv.x;
        y.y = (v.y - mu) * rstd * gv.y + bv.y;
        y.z = (v.z - mu) * rstd * gv.z + bv.z;
        y.w = (v.w - mu) * rstd * gv.w + bv.w;
        *(float4*)&ybuf[4 * i] = y;
        mx = fmaxf(mx, fmaxf(fmaxf(fabsf(y.x), fabsf(y.y)),
                             fmaxf(fabsf(y.z), fabsf(y.w))));
    }
#pragma unroll
    for (int off = 32; off; off >>= 1) mx = fmaxf(mx, __shfl_down(mx, off));
    int lane = tid & 63, w = tid >> 6;
    __syncthreads();
    if (lane == 0) red[w] = mx;
    __syncthreads();
    float rmax = fmaxf(fmaxf(fmaxf(red[0], red[1]), fmaxf(red[2], red[3])), 1e-30f);
    float inv = 127.f / rmax;
    if (tid == 0) sA[row] = rmax * (1.f / 127.f);

    uint8_t* arow = Aq + (size_t)row * ((size_t)D * 2);
    for (int i = tid; i < nvec; i += 256) {
        float4 y = *(float4*)&ybuf[4 * i];
        float qv[4] = { y.x * inv, y.y * inv, y.z * inv, y.w * inv };
        uint32_t u1 = 0, u2 = 0;
#pragma unroll
        for (int j = 0; j < 4; ++j) {
            float q1 = rintf(qv[j]);
            float q2 = rintf((qv[j] - q1) * 128.f);
            u1 |= ((uint32_t)((int)q1 & 0xFF)) << (8 * j);
            u2 |= ((uint32_t)((int)q2 & 0xFF)) << (8 * j);
        }
        int kt = i >> 4;          // (4i)/64
        int o = (i & 15) * 4;     // (4i)%64
        *(uint32_t*)(arow + kt * 128 + o) = u1;
        *(uint32_t*)(arow + kt * 128 + 64 + o) = u2;
    }
}

// ---------------------------------------------------------------------------
// conv_wq: W[K][N] fp32 -> dual-term i8, per-column scale.
// Wq[n][kt64][ b1 0..63 | b2 64..127 ], row stride 2K bytes. sB[n] scale.
// grid ceil(N/64), block 64.
// ---------------------------------------------------------------------------
__global__ __launch_bounds__(64)
void conv_wq(const float* __restrict__ W, uint8_t* __restrict__ Wq,
             float* __restrict__ sB, int K, int N) {
    int n = blockIdx.x * 64 + threadIdx.x;
    if (n >= N) return;
    float m = 0.f;
    for (int k = 0; k < K; ++k) m = fmaxf(m, fabsf(W[(size_t)k * N + n]));
    m = fmaxf(m, 1e-30f);
    float inv = 127.f / m;
    sB[n] = m * (1.f / 127.f);
    uint8_t* wrow = Wq + (size_t)n * ((size_t)K * 2);
    for (int kt = 0; kt < (K >> 6); ++kt) {
        for (int o = 0; o < 64; o += 4) {
            uint32_t u1 = 0, u2 = 0;
#pragma unroll
            for (int j = 0; j < 4; ++j) {
                float q = W[(size_t)(kt * 64 + o + j) * N + n] * inv;
                float q1 = rintf(q);
                float q2 = rintf((q - q1) * 128.f);
                u1 |= ((uint32_t)((int)q1 & 0xFF)) << (8 * j);
                u2 |= ((uint32_t)((int)q2 & 0xFF)) << (8 * j);
            }
            *(uint32_t*)(wrow + kt * 128 + o) = u1;
            *(uint32_t*)(wrow + kt * 128 + 64 + o) = u2;
        }
    }
}

// ---------------------------------------------------------------------------
// Dual-term i8 MFMA GEMM. out = sA[r]*sB[c]*(P + Q/128) + bias (+relu/+res).
//   P = a1@b1 (i32 exact), Q = a1@b2 + a2@b1 (shared i32 accumulator).
// 256x128 tile, BK=64 (one mfma_i32_16x16x64_i8 k-chunk), 8 waves (4M x 2N),
// per-wave out 64x64 (4x4 frags, accP+accQ = 128 VGPR). Double-buffered LDS
// (2 x 48KB), issue-early staging, ONE barrier per chunk (round-7 proven
// schedule). 128B/row chunk layout + row&7 XOR swizzle via pre-swizzled
// global source (identical addressing to the verified bf16 kernel).
// MODE 0: C = relu(v); 1: C += relu(v); 2: C = v.
// Requires M%256==0, N%128==0, K%64==0, grid (M/256, N/128), nwg%8==0.
// ---------------------------------------------------------------------------
template <int MODE>
__global__ __launch_bounds__(512, 2)
void gemm_i8(const uint8_t* __restrict__ Aq, const uint8_t* __restrict__ Bq,
             const float* __restrict__ sA, const float* __restrict__ sB,
             const float* __restrict__ bias, float* __restrict__ C,
             int M, int N, int K) {
    __shared__ char Abuf[2][32768];   // 256 rows x 128B
    __shared__ char Bbuf[2][16384];   // 128 rows x 128B

    const int tid = threadIdx.x;
    const int lane = tid & 63;
    const int wv = tid >> 6;       // 0..7
    const int wr = wv >> 1;        // 0..3  (M)
    const int wc = wv & 1;         // 0..1  (N)

    // T1 XCD-chunked swizzle (nwg % 8 == 0)
    int lid = blockIdx.y * gridDim.x + blockIdx.x;
    int nwg = gridDim.x * gridDim.y;
    int chunk = nwg >> 3;
    int swz = (lid & 7) * chunk + (lid >> 3);
    int nIdx = swz % gridDim.y;
    int mIdx = swz / gridDim.y;
    const int m0 = mIdx * 256, n0 = nIdx * 128;

    const int nt = K >> 6;               // BK = 64
    const size_t rowB = (size_t)K * 2;   // quantized row bytes

    // staging: A 2048 slots (4/thread), B 1024 slots (2/thread); 8 slots/row.
    int arow[4], aq[4];
#pragma unroll
    for (int i = 0; i < 4; ++i) {
        int s = i * 512 + tid;
        arow[i] = s >> 3;
        aq[i] = (s & 7) ^ (arow[i] & 7);
    }
    int brow[2], bq[2];
#pragma unroll
    for (int i = 0; i < 2; ++i) {
        int s = i * 512 + tid;
        brow[i] = s >> 3;
        bq[i] = (s & 7) ^ (brow[i] & 7);
    }

    i32x4 accP[4][4] = {};
    i32x4 accQ[4][4] = {};

    // prologue: stage chunk 0 into buffer 0
#pragma unroll
    for (int i = 0; i < 4; ++i)
        gload_lds16((const char*)Aq + (size_t)(m0 + arow[i]) * rowB + aq[i] * 16,
                    Abuf[0] + (i * 512 + tid) * 16);
#pragma unroll
    for (int i = 0; i < 2; ++i)
        gload_lds16((const char*)Bq + (size_t)(n0 + brow[i]) * rowB + bq[i] * 16,
                    Bbuf[0] + (i * 512 + tid) * 16);
    __syncthreads();

    int p = 0;
    const int g = lane >> 4;
    const int rr = lane & 15;

    for (int kt = 0; kt < nt; ++kt) {
        if (kt + 1 < nt) {
            const size_t koff = (size_t)(kt + 1) * 128;
#pragma unroll
            for (int i = 0; i < 4; ++i)
                gload_lds16((const char*)Aq + (size_t)(m0 + arow[i]) * rowB + koff + aq[i] * 16,
                            Abuf[p ^ 1] + (i * 512 + tid) * 16);
#pragma unroll
            for (int i = 0; i < 2; ++i)
                gload_lds16((const char*)Bq + (size_t)(n0 + brow[i]) * rowB + koff + bq[i] * 16,
                            Bbuf[p ^ 1] + (i * 512 + tid) * 16);
        }

        const char* Ab = Abuf[p];
        const char* Bb = Bbuf[p];

        // P: a1 x b1
        i32x4 a1[4], b1[4];
#pragma unroll
        for (int m = 0; m < 4; ++m) {
            int rA = wr * 64 + m * 16 + rr;
            a1[m] = *(const i32x4*)(Ab + rA * 128 + ((g ^ (rA & 7)) * 16));
        }
#pragma unroll
        for (int n = 0; n < 4; ++n) {
            int rB = wc * 64 + n * 16 + rr;
            b1[n] = *(const i32x4*)(Bb + rB * 128 + ((g ^ (rB & 7)) * 16));
        }
#pragma unroll
        for (int m = 0; m < 4; ++m)
#pragma unroll
            for (int n = 0; n < 4; ++n)
                accP[m][n] = __builtin_amdgcn_mfma_i32_16x16x64_i8(a1[m], b1[n], accP[m][n], 0, 0, 0);

        // Q += a1 x b2
        {
            i32x4 b2[4];
#pragma unroll
            for (int n = 0; n < 4; ++n) {
                int rB = wc * 64 + n * 16 + rr;
                b2[n] = *(const i32x4*)(Bb + rB * 128 + (((g + 4) ^ (rB & 7)) * 16));
            }
#pragma unroll
            for (int m = 0; m < 4; ++m)
#pragma unroll
                for (int n = 0; n < 4; ++n)
                    accQ[m][n] = __builtin_amdgcn_mfma_i32_16x16x64_i8(a1[m], b2[n], accQ[m][n], 0, 0, 0);
        }
        // Q += a2 x b1
        {
            i32x4 a2[4];
#pragma unroll
            for (int m = 0; m < 4; ++m) {
                int rA = wr * 64 + m * 16 + rr;
                a2[m] = *(const i32x4*)(Ab + rA * 128 + (((g + 4) ^ (rA & 7)) * 16));
            }
#pragma unroll
            for (int m = 0; m < 4; ++m)
#pragma unroll
                for (int n = 0; n < 4; ++n)
                    accQ[m][n] = __builtin_amdgcn_mfma_i32_16x16x64_i8(a2[m], b1[n], accQ[m][n], 0, 0, 0);
        }

        __syncthreads();
        p ^= 1;
    }

    // epilogue: C/D layout col = lane&15, row = (lane>>4)*4 + j  [m89/m91]
#pragma unroll
    for (int m = 0; m < 4; ++m) {
        int rbase = m0 + wr * 64 + m * 16 + (lane >> 4) * 4;
#pragma unroll
        for (int n = 0; n < 4; ++n) {
            int c = n0 + wc * 64 + n * 16 + (lane & 15);
            float sbc = sB[c];
            float bv = bias[c];
#pragma unroll
            for (int j = 0; j < 4; ++j) {
                int r = rbase + j;
                float v = sA[r] * sbc *
                          ((float)accP[m][n][j] + 0.0078125f * (float)accQ[m][n][j]) + bv;
                float* cp = &C[(size_t)r * N + c];
                if (MODE == 0) *cp = fmaxf(v, 0.f);
                else if (MODE == 1) *cp = *cp + fmaxf(v, 0.f);
                else *cp = v;
            }
        }
    }
}

// ---------------------------------------------------------------------------
// 16-wide simultaneous block reduction: v[16] per thread -> out[16] (shared).
// ---------------------------------------------------------------------------
template <bool MAXOP>
__device__ __forceinline__ void red16(const float* v, float* out, float (*scr)[4]) {
    int lane = threadIdx.x & 63, wv = threadIdx.x >> 6, tid = threadIdx.x;
#pragma unroll
    for (int oo = 0; oo < 16; ++oo) {
        float r = v[oo];
#pragma unroll
        for (int m = 1; m < 64; m <<= 1) {
            float t = __shfl_xor(r, m);
            r = MAXOP ? fmaxf(r, t) : r + t;
        }
        if (lane == 0) scr[oo][wv] = r;
    }
    __syncthreads();
    if (tid < 16) {
        float a = scr[tid][0], b = scr[tid][1], c = scr[tid][2], d = scr[tid][3];
        out[tid] = MAXOP ? fmaxf(fmaxf(a, b), fmaxf(c, d)) : (a + b + c + d);
    }
    __syncthreads();
}

// ---------------------------------------------------------------------------
// Attention over time, 16 outputs per block. grid = 64 bs * 8 ogroups.
// P=2 j-blocking (round-7, proven).
// ---------------------------------------------------------------------------
__global__ __launch_bounds__(256)
void attn_g16(const float* __restrict__ fc,
              const float* __restrict__ g1, const float* __restrict__ b1,
              const float* __restrict__ Wa1, const float* __restrict__ ba1,
              const float* __restrict__ g2, const float* __restrict__ b2,
              const float* __restrict__ Wa2, const float* __restrict__ ba2,
              float* __restrict__ out) {
    __shared__ float buf[257][20];
    __shared__ float scr[16][4];
    __shared__ float sS[16], sQ[16], sO[16];

    int bs = blockIdx.x >> 3;
    int o0 = (blockIdx.x & 7) * 16;
    int tid = threadIdx.x;
    int jgrp = tid >> 1;
    int kp = tid & 1;

    float vv[16], tmp[16];
    const float4* fp = (const float4*)(fc + (size_t)(bs * 256 + tid) * 128 + o0);
#pragma unroll
    for (int q = 0; q < 4; ++q) {
        float4 t = fp[q];
        vv[4 * q] = t.x; vv[4 * q + 1] = t.y; vv[4 * q + 2] = t.z; vv[4 * q + 3] = t.w;
    }

#pragma unroll
    for (int oo = 0; oo < 16; ++oo) tmp[oo] = vv[oo] * vv[oo];
    red16<false>(vv, sS, scr);
    red16<false>(tmp, sQ, scr);

    float gl = g1[tid], bl = b1[tid];
#pragma unroll
    for (int oo = 0; oo < 16; ++oo) {
        float s = sS[oo], q = sQ[oo];
        float mean = s * (1.f / 256.f);
        float mu = (s + mean) * (1.f / 257.f);
        float var = (q + mean * mean) * (1.f / 257.f) - mu * mu;
        float rstd = rsqrtf(var + EPSV);
        tmp[oo] = (vv[oo] - mu) * rstd * gl + bl;
    }
#pragma unroll
    for (int q = 0; q < 4; ++q)
        *(float4*)&buf[tid][4 * q] = *(float4*)&tmp[4 * q];
    if (tid < 16) {
        int oo = tid;
        float s = sS[oo], q = sQ[oo];
        float mean = s * (1.f / 256.f);
        float mu = (s + mean) * (1.f / 257.f);
        float var = (q + mean * mean) * (1.f / 257.f) - mu * mu;
        float rstd = rsqrtf(var + EPSV);
        buf[256][oo] = (mean - mu) * rstd * g1[256] + b1[256];
    }
    __syncthreads();

    float acc1[16][2] = {};
#pragma unroll 2
    for (int i = 0; i < 128; ++i) {
        int k = 2 * i + kp;
        float2 wv2 = *(const float2*)&Wa1[(size_t)k * 256 + jgrp * 2];
        float4 t0 = *(const float4*)&buf[k][0];
        float4 t1 = *(const float4*)&buf[k][4];
        float4 t2 = *(const float4*)&buf[k][8];
        float4 t3 = *(const float4*)&buf[k][12];
        float bv[16] = { t0.x, t0.y, t0.z, t0.w, t1.x, t1.y, t1.z, t1.w,
                         t2.x, t2.y, t2.z, t2.w, t3.x, t3.y, t3.z, t3.w };
#pragma unroll
        for (int oo = 0; oo < 16; ++oo) {
            acc1[oo][0] = fmaf(bv[oo], wv2.x, acc1[oo][0]);
            acc1[oo][1] = fmaf(bv[oo], wv2.y, acc1[oo][1]);
        }
    }
    if (kp == 0) {
        float2 wv2 = *(const float2*)&Wa1[(size_t)256 * 256 + jgrp * 2];
#pragma unroll
        for (int oo = 0; oo < 16; ++oo) {
            float bv = buf[256][oo];
            acc1[oo][0] = fmaf(bv, wv2.x, acc1[oo][0]);
            acc1[oo][1] = fmaf(bv, wv2.y, acc1[oo][1]);
        }
    }
    float a_[16];
#pragma unroll
    for (int oo = 0; oo < 16; ++oo) {
        float p0 = acc1[oo][0] + __shfl_xor(acc1[oo][0], 1);
        float p1 = acc1[oo][1] + __shfl_xor(acc1[oo][1], 1);
        a_[oo] = kp ? p1 : p0;
    }
    float bb = ba1[tid];
#pragma unroll
    for (int oo = 0; oo < 16; ++oo) a_[oo] = fmaxf(a_[oo] + bb, 0.f);

#pragma unroll
    for (int oo = 0; oo < 16; ++oo) tmp[oo] = a_[oo] * a_[oo];
    red16<false>(a_, sS, scr);
    red16<false>(tmp, sQ, scr);

    float g2l = g2[tid], b2l = b2[tid];
#pragma unroll
    for (int oo = 0; oo < 16; ++oo) {
        float mu2 = sS[oo] * (1.f / 256.f);
        float rstd2 = rsqrtf(sQ[oo] * (1.f / 256.f) - mu2 * mu2 + EPSV);
        tmp[oo] = (a_[oo] - mu2) * rstd2 * g2l + b2l;
    }
#pragma unroll
    for (int q = 0; q < 4; ++q)
        *(float4*)&buf[tid][4 * q] = *(float4*)&tmp[4 * q];
    __syncthreads();

    float acc2[16][2] = {};
#pragma unroll 2
    for (int i = 0; i < 128; ++i) {
        int k = 2 * i + kp;
        float2 wv2 = *(const float2*)&Wa2[(size_t)k * 256 + jgrp * 2];
        float4 t0 = *(const float4*)&buf[k][0];
        float4 t1 = *(const float4*)&buf[k][4];
        float4 t2 = *(const float4*)&buf[k][8];
        float4 t3 = *(const float4*)&buf[k][12];
        float bv[16] = { t0.x, t0.y, t0.z, t0.w, t1.x, t1.y, t1.z, t1.w,
                         t2.x, t2.y, t2.z, t2.w, t3.x, t3.y, t3.z, t3.w };
#pragma unroll
        for (int oo = 0; oo < 16; ++oo) {
            acc2[oo][0] = fmaf(bv[oo], wv2.x, acc2[oo][0]);
            acc2[oo][1] = fmaf(bv[oo], wv2.y, acc2[oo][1]);
        }
    }
    float w_[16];
#pragma unroll
    for (int oo = 0; oo < 16; ++oo) {
        float p0 = acc2[oo][0] + __shfl_xor(acc2[oo][0], 1);
        float p1 = acc2[oo][1] + __shfl_xor(acc2[oo][1], 1);
        w_[oo] = kp ? p1 : p0;
    }
    float bb2 = ba2[tid];
#pragma unroll
    for (int oo = 0; oo < 16; ++oo) w_[oo] += bb2;

    red16<true>(w_, sO, scr);
    float e_[16];
#pragma unroll
    for (int oo = 0; oo < 16; ++oo) e_[oo] = __expf(w_[oo] - sO[oo]);
    red16<false>(e_, sS, scr);
#pragma unroll
    for (int oo = 0; oo < 16; ++oo) tmp[oo] = vv[oo] * e_[oo] / sS[oo];
    red16<false>(tmp, sQ, scr);
    if (tid < 16) out[bs * 128 + o0 + tid] = sQ[tid];
}

// ---------------------------------------------------------------------------
// Launch
// ---------------------------------------------------------------------------
extern "C" void kernel_launch(void* const* d_in, const int* in_sizes, int n_in,
                              void* d_out, int out_size, void* d_ws, size_t ws_size,
                              hipStream_t stream) {
    const float* x      = (const float*)d_in[0];
    const float* ln0_g  = (const float*)d_in[1];
    const float* ln0_b  = (const float*)d_in[2];
    const float* W0     = (const float*)d_in[3];
    const float* b0     = (const float*)d_in[4];
    const float* rln_g  = (const float*)d_in[5];
    const float* rln_b  = (const float*)d_in[6];
    const float* rW     = (const float*)d_in[7];
    const float* rb     = (const float*)d_in[8];
    const float* lnf_g  = (const float*)d_in[9];
    const float* lnf_b  = (const float*)d_in[10];
    const float* Wf     = (const float*)d_in[11];
    const float* bf_    = (const float*)d_in[12];
    const float* ln1_g  = (const float*)d_in[13];
    const float* ln1_b  = (const float*)d_in[14];
    const float* Wa1    = (const float*)d_in[15];
    const float* ba1    = (const float*)d_in[16];
    const float* ln2_g  = (const float*)d_in[17];
    const float* ln2_b  = (const float*)d_in[18];
    const float* Wa2    = (const float*)d_in[19];
    const float* ba2    = (const float*)d_in[20];
    float* out = (float*)d_out;

    const int R = 64 * 256;   // 16384 rows
    float*    h   = (float*)d_ws;                        // R*1024 f32 (64 MB)
    uint8_t*  Aq  = (uint8_t*)(h + (size_t)R * 1024);    // R*2048 u8  (32 MB)
    float*    fc  = (float*)(Aq + (size_t)R * 2048);     // R*128 f32  (8 MB)
    uint8_t*  Wq  = (uint8_t*)(fc + (size_t)R * 128);    // 1024*2048 u8 (2 MB)
    float*    sA  = (float*)(Wq + (size_t)1024 * 2048);  // R floats
    float*    sBv = sA + R;                              // 1024 floats

    // stem: h = relu(LN(x) @ W0 + b0)
    conv_wq<<<16, 64, 0, stream>>>(W0, Wq, sBv, 512, 1024);
    ln_quant<<<R, 256, 0, stream>>>(x, ln0_g, ln0_b, Aq, sA, 512);
    gemm_i8<0><<<dim3(64, 8), 512, 0, stream>>>(Aq, Wq, sA, sBv, b0, h, R, 1024, 512);

    // residual blocks
    for (int i = 0; i < 8; ++i) {
        conv_wq<<<16, 64, 0, stream>>>(rW + (size_t)i * 1024 * 1024, Wq, sBv, 1024, 1024);
        ln_quant<<<R, 256, 0, stream>>>(h, rln_g + i * 1024, rln_b + i * 1024, Aq, sA, 1024);
        gemm_i8<1><<<dim3(64, 8), 512, 0, stream>>>(Aq, Wq, sA, sBv, rb + i * 1024, h, R, 1024, 1024);
    }

    // head: fc = LN(h) @ Wf + bf   (N = 128 -> grid (64,1))
    conv_wq<<<2, 64, 0, stream>>>(Wf, Wq, sBv, 1024, 128);
    ln_quant<<<R, 256, 0, stream>>>(h, lnf_g, lnf_b, Aq, sA, 1024);
    gemm_i8<2><<<dim3(64, 1), 512, 0, stream>>>(Aq, Wq, sA, sBv, bf_, fc, R, 128, 1024);

    // fused attention + weighted sum (16 outputs per block)
    attn_g16<<<64 * 8, 256, 0, stream>>>(fc, ln1_g, ln1_b, Wa1, ba1,
                                         ln2_g, ln2_b, Wa2, ba2, out);
}

// Round 11
// 1527.390 us; speedup vs baseline: 2.4149x; 2.4149x over previous
//
#include <hip/hip_runtime.h>
#include <hip/hip_bf16.h>
#include <stdint.h>

#define EPSV 1e-5f

typedef int i32x4 __attribute__((ext_vector_type(4)));

__device__ __forceinline__ void gload_lds16(const void* g, void* l) {
    __builtin_amdgcn_global_load_lds(
        (const __attribute__((address_space(1))) uint32_t*)g,
        (__attribute__((address_space(3))) uint32_t*)l, 16, 0, 0);
}

// ---------------------------------------------------------------------------
// Block reduction helpers (256 threads = 4 waves of 64)
// ---------------------------------------------------------------------------
__device__ __forceinline__ float block_sum256(float v, float* red) {
#pragma unroll
    for (int off = 32; off; off >>= 1) v += __shfl_down(v, off);
    int lane = threadIdx.x & 63, w = threadIdx.x >> 6;
    __syncthreads();
    if (lane == 0) red[w] = v;
    __syncthreads();
    return red[0] + red[1] + red[2] + red[3];
}

// ---------------------------------------------------------------------------
// ln_quant: row LayerNorm -> dual-term i8 quantized output + per-row scale.
// Layout: Aq[row][kt64][ a1 bytes 0..63 | a2 bytes 64..127 ], row stride 2K B.
// y = LN(x)*g + b;  y ~= sA[row] * (a1 + a2/128),  |err| <= rowmax * 2^-15.
// ---------------------------------------------------------------------------
__global__ __launch_bounds__(256)
void ln_quant(const float* __restrict__ X, const float* __restrict__ g,
              const float* __restrict__ b, uint8_t* __restrict__ Aq,
              float* __restrict__ sA, int D) {
    __shared__ float red[4];
    __shared__ float ybuf[1024];
    int row = blockIdx.x;
    const float* x = X + (size_t)row * D;
    int tid = threadIdx.x;
    int nvec = D >> 2;

    float s = 0.f, sq = 0.f;
    for (int i = tid; i < nvec; i += 256) {
        float4 v = ((const float4*)x)[i];
        s += v.x + v.y + v.z + v.w;
        sq += v.x * v.x + v.y * v.y + v.z * v.z + v.w * v.w;
    }
    float ts = block_sum256(s, red);
    float tq = block_sum256(sq, red);
    float invD = 1.f / (float)D;
    float mu = ts * invD;
    float rstd = rsqrtf(tq * invD - mu * mu + EPSV);

    float mx = 0.f;
    for (int i = tid; i < nvec; i += 256) {
        float4 v = ((const float4*)x)[i];
        float4 gv = ((const float4*)g)[i];
        float4 bv = ((const float4*)b)[i];
        float4 y;
        y.x = (v.x - mu) * rstd * gv.x + bv.x;
        y.y = (v.y - mu) * rstd * gv.y + bv.y;
        y.z = (v.z - mu) * rstd * gv.z + bv.z;
        y.w = (v.w - mu) * rstd * gv.w + bv.w;
        *(float4*)&ybuf[4 * i] = y;
        mx = fmaxf(mx, fmaxf(fmaxf(fabsf(y.x), fabsf(y.y)),
                             fmaxf(fabsf(y.z), fabsf(y.w))));
    }
#pragma unroll
    for (int off = 32; off; off >>= 1) mx = fmaxf(mx, __shfl_down(mx, off));
    int lane = tid & 63, w = tid >> 6;
    __syncthreads();
    if (lane == 0) red[w] = mx;
    __syncthreads();
    float rmax = fmaxf(fmaxf(fmaxf(red[0], red[1]), fmaxf(red[2], red[3])), 1e-30f);
    float inv = 127.f / rmax;
    if (tid == 0) sA[row] = rmax * (1.f / 127.f);

    uint8_t* arow = Aq + (size_t)row * ((size_t)D * 2);
    for (int i = tid; i < nvec; i += 256) {
        float4 y = *(float4*)&ybuf[4 * i];
        float qv[4] = { y.x * inv, y.y * inv, y.z * inv, y.w * inv };
        uint32_t u1 = 0, u2 = 0;
#pragma unroll
        for (int j = 0; j < 4; ++j) {
            float q1 = rintf(qv[j]);
            float q2 = rintf((qv[j] - q1) * 128.f);
            u1 |= ((uint32_t)((int)q1 & 0xFF)) << (8 * j);
            u2 |= ((uint32_t)((int)q2 & 0xFF)) << (8 * j);
        }
        int kt = i >> 4;          // (4i)/64
        int o = (i & 15) * 4;     // (4i)%64
        *(uint32_t*)(arow + kt * 128 + o) = u1;
        *(uint32_t*)(arow + kt * 128 + 64 + o) = u2;
    }
}

// ---------------------------------------------------------------------------
// col_absmax: partial per-column abs-max of W[K][N] over 8 k-partitions.
// grid (8, ceil(N/256)), block 256. Coalesced (consecutive tid -> cols).
// ---------------------------------------------------------------------------
__global__ __launch_bounds__(256)
void col_absmax(const float* __restrict__ W, float* __restrict__ part,
                int K, int N) {
    int n = blockIdx.y * 256 + threadIdx.x;
    int kp = blockIdx.x;
    if (n >= N) return;
    int kc = K >> 3;
    int k0 = kp * kc;
    float m = 0.f;
    for (int k = k0; k < k0 + kc; ++k)
        m = fmaxf(m, fabsf(W[(size_t)k * N + n]));
    part[kp * N + n] = m;
}

// ---------------------------------------------------------------------------
// col_scale: sB[n] = (max over 8 partials)/127. grid ceil(N/256), block 256.
// ---------------------------------------------------------------------------
__global__ __launch_bounds__(256)
void col_scale(const float* __restrict__ part, float* __restrict__ sB, int N) {
    int n = blockIdx.x * 256 + threadIdx.x;
    if (n >= N) return;
    float m = 0.f;
#pragma unroll
    for (int kp = 0; kp < 8; ++kp) m = fmaxf(m, part[kp * N + n]);
    m = fmaxf(m, 1e-30f);
    sB[n] = m * (1.f / 127.f);
}

// ---------------------------------------------------------------------------
// conv_wq: quantize W[K][N] -> dual-term i8 using precomputed sB.
// Wq[n][kt64][ b1 0..63 | b2 64..127 ], row stride 2K bytes.
// grid (ceil(N/64), K/64), block 64: thread = column, 64-k strip per block.
// ---------------------------------------------------------------------------
__global__ __launch_bounds__(64)
void conv_wq(const float* __restrict__ W, const float* __restrict__ sB,
             uint8_t* __restrict__ Wq, int K, int N) {
    int n = blockIdx.x * 64 + threadIdx.x;
    int kt = blockIdx.y;
    if (n >= N) return;
    float inv = 1.f / sB[n];   // = 127/colmax
    uint32_t u1[16], u2[16];
#pragma unroll 4
    for (int o = 0; o < 16; ++o) {
        uint32_t a = 0, bq = 0;
#pragma unroll
        for (int j = 0; j < 4; ++j) {
            float q = W[(size_t)(kt * 64 + o * 4 + j) * N + n] * inv;
            float q1 = rintf(q);
            float q2 = rintf((q - q1) * 128.f);
            a |= ((uint32_t)((int)q1 & 0xFF)) << (8 * j);
            bq |= ((uint32_t)((int)q2 & 0xFF)) << (8 * j);
        }
        u1[o] = a; u2[o] = bq;
    }
    uint8_t* wrow = Wq + (size_t)n * ((size_t)K * 2) + kt * 128;
    uint4* d = (uint4*)wrow;
    const uint4* p1 = (const uint4*)u1;
    const uint4* p2 = (const uint4*)u2;
    d[0] = p1[0]; d[1] = p1[1]; d[2] = p1[2]; d[3] = p1[3];
    d[4] = p2[0]; d[5] = p2[1]; d[6] = p2[2]; d[7] = p2[3];
}

// ---------------------------------------------------------------------------
// Dual-term i8 MFMA GEMM. out = sA[r]*sB[c]*(P + Q/128) + bias (+relu/+res).
//   P = a1@b1 (i32 exact), Q = a1@b2 + a2@b1 (shared i32 accumulator).
// 256x128 tile, BK=64 (one mfma_i32_16x16x64_i8 k-chunk), 8 waves (4M x 2N),
// per-wave out 64x64. Double-buffered LDS (2 x 48KB), issue-early staging,
// ONE barrier per chunk (round-7 proven schedule). 128B/row chunk layout +
// row&7 XOR swizzle via pre-swizzled global source.
// MODE 0: C = relu(v); 1: C += relu(v); 2: C = v.
// Requires M%256==0, N%128==0, K%64==0, grid (M/256, N/128), nwg%8==0.
// ---------------------------------------------------------------------------
template <int MODE>
__global__ __launch_bounds__(512, 2)
void gemm_i8(const uint8_t* __restrict__ Aq, const uint8_t* __restrict__ Bq,
             const float* __restrict__ sA, const float* __restrict__ sB,
             const float* __restrict__ bias, float* __restrict__ C,
             int M, int N, int K) {
    __shared__ char Abuf[2][32768];   // 256 rows x 128B
    __shared__ char Bbuf[2][16384];   // 128 rows x 128B

    const int tid = threadIdx.x;
    const int lane = tid & 63;
    const int wv = tid >> 6;       // 0..7
    const int wr = wv >> 1;        // 0..3  (M)
    const int wc = wv & 1;         // 0..1  (N)

    // T1 XCD-chunked swizzle (nwg % 8 == 0)
    int lid = blockIdx.y * gridDim.x + blockIdx.x;
    int nwg = gridDim.x * gridDim.y;
    int chunk = nwg >> 3;
    int swz = (lid & 7) * chunk + (lid >> 3);
    int nIdx = swz % gridDim.y;
    int mIdx = swz / gridDim.y;
    const int m0 = mIdx * 256, n0 = nIdx * 128;

    const int nt = K >> 6;               // BK = 64
    const size_t rowB = (size_t)K * 2;   // quantized row bytes

    int arow[4], aq[4];
#pragma unroll
    for (int i = 0; i < 4; ++i) {
        int s = i * 512 + tid;
        arow[i] = s >> 3;
        aq[i] = (s & 7) ^ (arow[i] & 7);
    }
    int brow[2], bq[2];
#pragma unroll
    for (int i = 0; i < 2; ++i) {
        int s = i * 512 + tid;
        brow[i] = s >> 3;
        bq[i] = (s & 7) ^ (brow[i] & 7);
    }

    i32x4 accP[4][4] = {};
    i32x4 accQ[4][4] = {};

    // prologue: stage chunk 0 into buffer 0
#pragma unroll
    for (int i = 0; i < 4; ++i)
        gload_lds16((const char*)Aq + (size_t)(m0 + arow[i]) * rowB + aq[i] * 16,
                    Abuf[0] + (i * 512 + tid) * 16);
#pragma unroll
    for (int i = 0; i < 2; ++i)
        gload_lds16((const char*)Bq + (size_t)(n0 + brow[i]) * rowB + bq[i] * 16,
                    Bbuf[0] + (i * 512 + tid) * 16);
    __syncthreads();

    int p = 0;
    const int g = lane >> 4;
    const int rr = lane & 15;

    for (int kt = 0; kt < nt; ++kt) {
        if (kt + 1 < nt) {
            const size_t koff = (size_t)(kt + 1) * 128;
#pragma unroll
            for (int i = 0; i < 4; ++i)
                gload_lds16((const char*)Aq + (size_t)(m0 + arow[i]) * rowB + koff + aq[i] * 16,
                            Abuf[p ^ 1] + (i * 512 + tid) * 16);
#pragma unroll
            for (int i = 0; i < 2; ++i)
                gload_lds16((const char*)Bq + (size_t)(n0 + brow[i]) * rowB + koff + bq[i] * 16,
                            Bbuf[p ^ 1] + (i * 512 + tid) * 16);
        }

        const char* Ab = Abuf[p];
        const char* Bb = Bbuf[p];

        // P: a1 x b1
        i32x4 a1[4], b1[4];
#pragma unroll
        for (int m = 0; m < 4; ++m) {
            int rA = wr * 64 + m * 16 + rr;
            a1[m] = *(const i32x4*)(Ab + rA * 128 + ((g ^ (rA & 7)) * 16));
        }
#pragma unroll
        for (int n = 0; n < 4; ++n) {
            int rB = wc * 64 + n * 16 + rr;
            b1[n] = *(const i32x4*)(Bb + rB * 128 + ((g ^ (rB & 7)) * 16));
        }
#pragma unroll
        for (int m = 0; m < 4; ++m)
#pragma unroll
            for (int n = 0; n < 4; ++n)
                accP[m][n] = __builtin_amdgcn_mfma_i32_16x16x64_i8(a1[m], b1[n], accP[m][n], 0, 0, 0);

        // Q += a1 x b2
        {
            i32x4 b2[4];
#pragma unroll
            for (int n = 0; n < 4; ++n) {
                int rB = wc * 64 + n * 16 + rr;
                b2[n] = *(const i32x4*)(Bb + rB * 128 + (((g + 4) ^ (rB & 7)) * 16));
            }
#pragma unroll
            for (int m = 0; m < 4; ++m)
#pragma unroll
                for (int n = 0; n < 4; ++n)
                    accQ[m][n] = __builtin_amdgcn_mfma_i32_16x16x64_i8(a1[m], b2[n], accQ[m][n], 0, 0, 0);
        }
        // Q += a2 x b1
        {
            i32x4 a2[4];
#pragma unroll
            for (int m = 0; m < 4; ++m) {
                int rA = wr * 64 + m * 16 + rr;
                a2[m] = *(const i32x4*)(Ab + rA * 128 + (((g + 4) ^ (rA & 7)) * 16));
            }
#pragma unroll
            for (int m = 0; m < 4; ++m)
#pragma unroll
                for (int n = 0; n < 4; ++n)
                    accQ[m][n] = __builtin_amdgcn_mfma_i32_16x16x64_i8(a2[m], b1[n], accQ[m][n], 0, 0, 0);
        }

        __syncthreads();
        p ^= 1;
    }

    // epilogue: C/D layout col = lane&15, row = (lane>>4)*4 + j  [m89/m91]
#pragma unroll
    for (int m = 0; m < 4; ++m) {
        int rbase = m0 + wr * 64 + m * 16 + (lane >> 4) * 4;
#pragma unroll
        for (int n = 0; n < 4; ++n) {
            int c = n0 + wc * 64 + n * 16 + (lane & 15);
            float sbc = sB[c];
            float bv = bias[c];
#pragma unroll
            for (int j = 0; j < 4; ++j) {
                int r = rbase + j;
                float v = sA[r] * sbc *
                          ((float)accP[m][n][j] + 0.0078125f * (float)accQ[m][n][j]) + bv;
                float* cp = &C[(size_t)r * N + c];
                if (MODE == 0) *cp = fmaxf(v, 0.f);
                else if (MODE == 1) *cp = *cp + fmaxf(v, 0.f);
                else *cp = v;
            }
        }
    }
}

// ---------------------------------------------------------------------------
// 16-wide simultaneous block reduction: v[16] per thread -> out[16] (shared).
// ---------------------------------------------------------------------------
template <bool MAXOP>
__device__ __forceinline__ void red16(const float* v, float* out, float (*scr)[4]) {
    int lane = threadIdx.x & 63, wv = threadIdx.x >> 6, tid = threadIdx.x;
#pragma unroll
    for (int oo = 0; oo < 16; ++oo) {
        float r = v[oo];
#pragma unroll
        for (int m = 1; m < 64; m <<= 1) {
            float t = __shfl_xor(r, m);
            r = MAXOP ? fmaxf(r, t) : r + t;
        }
        if (lane == 0) scr[oo][wv] = r;
    }
    __syncthreads();
    if (tid < 16) {
        float a = scr[tid][0], b = scr[tid][1], c = scr[tid][2], d = scr[tid][3];
        out[tid] = MAXOP ? fmaxf(fmaxf(a, b), fmaxf(c, d)) : (a + b + c + d);
    }
    __syncthreads();
}

// ---------------------------------------------------------------------------
// Attention over time, 16 outputs per block. grid = 64 bs * 8 ogroups.
// P=2 j-blocking (round-7, proven).
// ---------------------------------------------------------------------------
__global__ __launch_bounds__(256)
void attn_g16(const float* __restrict__ fc,
              const float* __restrict__ g1, const float* __restrict__ b1,
              const float* __restrict__ Wa1, const float* __restrict__ ba1,
              const float* __restrict__ g2, const float* __restrict__ b2,
              const float* __restrict__ Wa2, const float* __restrict__ ba2,
              float* __restrict__ out) {
    __shared__ float buf[257][20];
    __shared__ float scr[16][4];
    __shared__ float sS[16], sQ[16], sO[16];

    int bs = blockIdx.x >> 3;
    int o0 = (blockIdx.x & 7) * 16;
    int tid = threadIdx.x;
    int jgrp = tid >> 1;
    int kp = tid & 1;

    float vv[16], tmp[16];
    const float4* fp = (const float4*)(fc + (size_t)(bs * 256 + tid) * 128 + o0);
#pragma unroll
    for (int q = 0; q < 4; ++q) {
        float4 t = fp[q];
        vv[4 * q] = t.x; vv[4 * q + 1] = t.y; vv[4 * q + 2] = t.z; vv[4 * q + 3] = t.w;
    }

#pragma unroll
    for (int oo = 0; oo < 16; ++oo) tmp[oo] = vv[oo] * vv[oo];
    red16<false>(vv, sS, scr);
    red16<false>(tmp, sQ, scr);

    float gl = g1[tid], bl = b1[tid];
#pragma unroll
    for (int oo = 0; oo < 16; ++oo) {
        float s = sS[oo], q = sQ[oo];
        float mean = s * (1.f / 256.f);
        float mu = (s + mean) * (1.f / 257.f);
        float var = (q + mean * mean) * (1.f / 257.f) - mu * mu;
        float rstd = rsqrtf(var + EPSV);
        tmp[oo] = (vv[oo] - mu) * rstd * gl + bl;
    }
#pragma unroll
    for (int q = 0; q < 4; ++q)
        *(float4*)&buf[tid][4 * q] = *(float4*)&tmp[4 * q];
    if (tid < 16) {
        int oo = tid;
        float s = sS[oo], q = sQ[oo];
        float mean = s * (1.f / 256.f);
        float mu = (s + mean) * (1.f / 257.f);
        float var = (q + mean * mean) * (1.f / 257.f) - mu * mu;
        float rstd = rsqrtf(var + EPSV);
        buf[256][oo] = (mean - mu) * rstd * g1[256] + b1[256];
    }
    __syncthreads();

    float acc1[16][2] = {};
#pragma unroll 2
    for (int i = 0; i < 128; ++i) {
        int k = 2 * i + kp;
        float2 wv2 = *(const float2*)&Wa1[(size_t)k * 256 + jgrp * 2];
        float4 t0 = *(const float4*)&buf[k][0];
        float4 t1 = *(const float4*)&buf[k][4];
        float4 t2 = *(const float4*)&buf[k][8];
        float4 t3 = *(const float4*)&buf[k][12];
        float bv[16] = { t0.x, t0.y, t0.z, t0.w, t1.x, t1.y, t1.z, t1.w,
                         t2.x, t2.y, t2.z, t2.w, t3.x, t3.y, t3.z, t3.w };
#pragma unroll
        for (int oo = 0; oo < 16; ++oo) {
            acc1[oo][0] = fmaf(bv[oo], wv2.x, acc1[oo][0]);
            acc1[oo][1] = fmaf(bv[oo], wv2.y, acc1[oo][1]);
        }
    }
    if (kp == 0) {
        float2 wv2 = *(const float2*)&Wa1[(size_t)256 * 256 + jgrp * 2];
#pragma unroll
        for (int oo = 0; oo < 16; ++oo) {
            float bv = buf[256][oo];
            acc1[oo][0] = fmaf(bv, wv2.x, acc1[oo][0]);
            acc1[oo][1] = fmaf(bv, wv2.y, acc1[oo][1]);
        }
    }
    float a_[16];
#pragma unroll
    for (int oo = 0; oo < 16; ++oo) {
        float p0 = acc1[oo][0] + __shfl_xor(acc1[oo][0], 1);
        float p1 = acc1[oo][1] + __shfl_xor(acc1[oo][1], 1);
        a_[oo] = kp ? p1 : p0;
    }
    float bb = ba1[tid];
#pragma unroll
    for (int oo = 0; oo < 16; ++oo) a_[oo] = fmaxf(a_[oo] + bb, 0.f);

#pragma unroll
    for (int oo = 0; oo < 16; ++oo) tmp[oo] = a_[oo] * a_[oo];
    red16<false>(a_, sS, scr);
    red16<false>(tmp, sQ, scr);

    float g2l = g2[tid], b2l = b2[tid];
#pragma unroll
    for (int oo = 0; oo < 16; ++oo) {
        float mu2 = sS[oo] * (1.f / 256.f);
        float rstd2 = rsqrtf(sQ[oo] * (1.f / 256.f) - mu2 * mu2 + EPSV);
        tmp[oo] = (a_[oo] - mu2) * rstd2 * g2l + b2l;
    }
#pragma unroll
    for (int q = 0; q < 4; ++q)
        *(float4*)&buf[tid][4 * q] = *(float4*)&tmp[4 * q];
    __syncthreads();

    float acc2[16][2] = {};
#pragma unroll 2
    for (int i = 0; i < 128; ++i) {
        int k = 2 * i + kp;
        float2 wv2 = *(const float2*)&Wa2[(size_t)k * 256 + jgrp * 2];
        float4 t0 = *(const float4*)&buf[k][0];
        float4 t1 = *(const float4*)&buf[k][4];
        float4 t2 = *(const float4*)&buf[k][8];
        float4 t3 = *(const float4*)&buf[k][12];
        float bv[16] = { t0.x, t0.y, t0.z, t0.w, t1.x, t1.y, t1.z, t1.w,
                         t2.x, t2.y, t2.z, t2.w, t3.x, t3.y, t3.z, t3.w };
#pragma unroll
        for (int oo = 0; oo < 16; ++oo) {
            acc2[oo][0] = fmaf(bv[oo], wv2.x, acc2[oo][0]);
            acc2[oo][1] = fmaf(bv[oo], wv2.y, acc2[oo][1]);
        }
    }
    float w_[16];
#pragma unroll
    for (int oo = 0; oo < 16; ++oo) {
        float p0 = acc2[oo][0] + __shfl_xor(acc2[oo][0], 1);
        float p1 = acc2[oo][1] + __shfl_xor(acc2[oo][1], 1);
        w_[oo] = kp ? p1 : p0;
    }
    float bb2 = ba2[tid];
#pragma unroll
    for (int oo = 0; oo < 16; ++oo) w_[oo] += bb2;

    red16<true>(w_, sO, scr);
    float e_[16];
#pragma unroll
    for (int oo = 0; oo < 16; ++oo) e_[oo] = __expf(w_[oo] - sO[oo]);
    red16<false>(e_, sS, scr);
#pragma unroll
    for (int oo = 0; oo < 16; ++oo) tmp[oo] = vv[oo] * e_[oo] / sS[oo];
    red16<false>(tmp, sQ, scr);
    if (tid < 16) out[bs * 128 + o0 + tid] = sQ[tid];
}

// ---------------------------------------------------------------------------
// Launch
// ---------------------------------------------------------------------------
extern "C" void kernel_launch(void* const* d_in, const int* in_sizes, int n_in,
                              void* d_out, int out_size, void* d_ws, size_t ws_size,
                              hipStream_t stream) {
    const float* x      = (const float*)d_in[0];
    const float* ln0_g  = (const float*)d_in[1];
    const float* ln0_b  = (const float*)d_in[2];
    const float* W0     = (const float*)d_in[3];
    const float* b0     = (const float*)d_in[4];
    const float* rln_g  = (const float*)d_in[5];
    const float* rln_b  = (const float*)d_in[6];
    const float* rW     = (const float*)d_in[7];
    const float* rb     = (const float*)d_in[8];
    const float* lnf_g  = (const float*)d_in[9];
    const float* lnf_b  = (const float*)d_in[10];
    const float* Wf     = (const float*)d_in[11];
    const float* bf_    = (const float*)d_in[12];
    const float* ln1_g  = (const float*)d_in[13];
    const float* ln1_b  = (const float*)d_in[14];
    const float* Wa1    = (const float*)d_in[15];
    const float* ba1    = (const float*)d_in[16];
    const float* ln2_g  = (const float*)d_in[17];
    const float* ln2_b  = (const float*)d_in[18];
    const float* Wa2    = (const float*)d_in[19];
    const float* ba2    = (const float*)d_in[20];
    float* out = (float*)d_out;

    const int R = 64 * 256;   // 16384 rows
    float*    h    = (float*)d_ws;                        // R*1024 f32 (64 MB)
    uint8_t*  Aq   = (uint8_t*)(h + (size_t)R * 1024);    // R*2048 u8  (32 MB)
    float*    fc   = (float*)(Aq + (size_t)R * 2048);     // R*128 f32  (8 MB)
    uint8_t*  Wq   = (uint8_t*)(fc + (size_t)R * 128);    // 1024*2048 u8 (2 MB)
    float*    sA   = (float*)(Wq + (size_t)1024 * 2048);  // R floats
    float*    sBv  = sA + R;                              // 1024 floats
    float*    part = sBv + 1024;                          // 8*1024 floats

    // stem: h = relu(LN(x) @ W0 + b0)
    col_absmax<<<dim3(8, 4), 256, 0, stream>>>(W0, part, 512, 1024);
    col_scale<<<4, 256, 0, stream>>>(part, sBv, 1024);
    conv_wq<<<dim3(16, 8), 64, 0, stream>>>(W0, sBv, Wq, 512, 1024);
    ln_quant<<<R, 256, 0, stream>>>(x, ln0_g, ln0_b, Aq, sA, 512);
    gemm_i8<0><<<dim3(64, 8), 512, 0, stream>>>(Aq, Wq, sA, sBv, b0, h, R, 1024, 512);

    // residual blocks
    for (int i = 0; i < 8; ++i) {
        const float* Wi = rW + (size_t)i * 1024 * 1024;
        col_absmax<<<dim3(8, 4), 256, 0, stream>>>(Wi, part, 1024, 1024);
        col_scale<<<4, 256, 0, stream>>>(part, sBv, 1024);
        conv_wq<<<dim3(16, 16), 64, 0, stream>>>(Wi, sBv, Wq, 1024, 1024);
        ln_quant<<<R, 256, 0, stream>>>(h, rln_g + i * 1024, rln_b + i * 1024, Aq, sA, 1024);
        gemm_i8<1><<<dim3(64, 8), 512, 0, stream>>>(Aq, Wq, sA, sBv, rb + i * 1024, h, R, 1024, 1024);
    }

    // head: fc = LN(h) @ Wf + bf   (N = 128 -> grid (64,1))
    col_absmax<<<dim3(8, 1), 256, 0, stream>>>(Wf, part, 1024, 128);
    col_scale<<<1, 256, 0, stream>>>(part, sBv, 128);
    conv_wq<<<dim3(2, 16), 64, 0, stream>>>(Wf, sBv, Wq, 1024, 128);
    ln_quant<<<R, 256, 0, stream>>>(h, lnf_g, lnf_b, Aq, sA, 1024);
    gemm_i8<2><<<dim3(64, 1), 512, 0, stream>>>(Aq, Wq, sA, sBv, bf_, fc, R, 128, 1024);

    // fused attention + weighted sum (16 outputs per block)
    attn_g16<<<64 * 8, 256, 0, stream>>>(fc, ln1_g, ln1_b, Wa1, ba1,
                                         ln2_g, ln2_b, Wa2, ba2, out);
}

// Round 12
// 1101.884 us; speedup vs baseline: 3.3474x; 1.3862x over previous
//
#include <hip/hip_runtime.h>
#include <hip/hip_bf16.h>
#include <stdint.h>

#define EPSV 1e-5f

typedef int i32x4 __attribute__((ext_vector_type(4)));

__device__ __forceinline__ void gload_lds16(const void* g, void* l) {
    __builtin_amdgcn_global_load_lds(
        (const __attribute__((address_space(1))) uint32_t*)g,
        (__attribute__((address_space(3))) uint32_t*)l, 16, 0, 0);
}

// ---------------------------------------------------------------------------
// Block reduction helpers (256 threads = 4 waves of 64)
// ---------------------------------------------------------------------------
__device__ __forceinline__ float block_sum256(float v, float* red) {
#pragma unroll
    for (int off = 32; off; off >>= 1) v += __shfl_down(v, off);
    int lane = threadIdx.x & 63, w = threadIdx.x >> 6;
    __syncthreads();
    if (lane == 0) red[w] = v;
    __syncthreads();
    return red[0] + red[1] + red[2] + red[3];
}

// ---------------------------------------------------------------------------
// ln_quant: row LayerNorm -> dual-term i8 quantized output + per-row scale.
// Layout: Aq[row][kt64][ a1 bytes 0..63 | a2 bytes 64..127 ], row stride 2K B.
// ---------------------------------------------------------------------------
__global__ __launch_bounds__(256)
void ln_quant(const float* __restrict__ X, const float* __restrict__ g,
              const float* __restrict__ b, uint8_t* __restrict__ Aq,
              float* __restrict__ sA, int D) {
    __shared__ float red[4];
    __shared__ float ybuf[1024];
    int row = blockIdx.x;
    const float* x = X + (size_t)row * D;
    int tid = threadIdx.x;
    int nvec = D >> 2;

    float s = 0.f, sq = 0.f;
    for (int i = tid; i < nvec; i += 256) {
        float4 v = ((const float4*)x)[i];
        s += v.x + v.y + v.z + v.w;
        sq += v.x * v.x + v.y * v.y + v.z * v.z + v.w * v.w;
    }
    float ts = block_sum256(s, red);
    float tq = block_sum256(sq, red);
    float invD = 1.f / (float)D;
    float mu = ts * invD;
    float rstd = rsqrtf(tq * invD - mu * mu + EPSV);

    float mx = 0.f;
    for (int i = tid; i < nvec; i += 256) {
        float4 v = ((const float4*)x)[i];
        float4 gv = ((const float4*)g)[i];
        float4 bv = ((const float4*)b)[i];
        float4 y;
        y.x = (v.x - mu) * rstd * gv.x + bv.x;
        y.y = (v.y - mu) * rstd * gv.y + bv.y;
        y.z = (v.z - mu) * rstd * gv.z + bv.z;
        y.w = (v.w - mu) * rstd * gv.w + bv.w;
        *(float4*)&ybuf[4 * i] = y;
        mx = fmaxf(mx, fmaxf(fmaxf(fabsf(y.x), fabsf(y.y)),
                             fmaxf(fabsf(y.z), fabsf(y.w))));
    }
#pragma unroll
    for (int off = 32; off; off >>= 1) mx = fmaxf(mx, __shfl_down(mx, off));
    int lane = tid & 63, w = tid >> 6;
    __syncthreads();
    if (lane == 0) red[w] = mx;
    __syncthreads();
    float rmax = fmaxf(fmaxf(fmaxf(red[0], red[1]), fmaxf(red[2], red[3])), 1e-30f);
    float inv = 127.f / rmax;
    if (tid == 0) sA[row] = rmax * (1.f / 127.f);

    uint8_t* arow = Aq + (size_t)row * ((size_t)D * 2);
    for (int i = tid; i < nvec; i += 256) {
        float4 y = *(float4*)&ybuf[4 * i];
        float qv[4] = { y.x * inv, y.y * inv, y.z * inv, y.w * inv };
        uint32_t u1 = 0, u2 = 0;
#pragma unroll
        for (int j = 0; j < 4; ++j) {
            float q1 = rintf(qv[j]);
            float q2 = rintf((qv[j] - q1) * 128.f);
            u1 |= ((uint32_t)((int)q1 & 0xFF)) << (8 * j);
            u2 |= ((uint32_t)((int)q2 & 0xFF)) << (8 * j);
        }
        int kt = i >> 4;
        int o = (i & 15) * 4;
        *(uint32_t*)(arow + kt * 128 + o) = u1;
        *(uint32_t*)(arow + kt * 128 + 64 + o) = u2;
    }
}

// ---------------------------------------------------------------------------
// Weight quantization (per-matrix kernels, used for W0 / Wf)
// ---------------------------------------------------------------------------
__global__ __launch_bounds__(256)
void col_absmax(const float* __restrict__ W, float* __restrict__ part,
                int K, int N) {
    int n = blockIdx.y * 256 + threadIdx.x;
    int kp = blockIdx.x;
    if (n >= N) return;
    int kc = K >> 3;
    int k0 = kp * kc;
    float m = 0.f;
    for (int k = k0; k < k0 + kc; ++k)
        m = fmaxf(m, fabsf(W[(size_t)k * N + n]));
    part[kp * N + n] = m;
}

__global__ __launch_bounds__(256)
void col_scale(const float* __restrict__ part, float* __restrict__ sB, int N) {
    int n = blockIdx.x * 256 + threadIdx.x;
    if (n >= N) return;
    float m = 0.f;
#pragma unroll
    for (int kp = 0; kp < 8; ++kp) m = fmaxf(m, part[kp * N + n]);
    m = fmaxf(m, 1e-30f);
    sB[n] = m * (1.f / 127.f);
}

__global__ __launch_bounds__(64)
void conv_wq(const float* __restrict__ W, const float* __restrict__ sB,
             uint8_t* __restrict__ Wq, int K, int N) {
    int n = blockIdx.x * 64 + threadIdx.x;
    int kt = blockIdx.y;
    if (n >= N) return;
    float inv = 1.f / sB[n];
    uint32_t u1[16], u2[16];
#pragma unroll 4
    for (int o = 0; o < 16; ++o) {
        uint32_t a = 0, bq = 0;
#pragma unroll
        for (int j = 0; j < 4; ++j) {
            float q = W[(size_t)(kt * 64 + o * 4 + j) * N + n] * inv;
            float q1 = rintf(q);
            float q2 = rintf((q - q1) * 128.f);
            a |= ((uint32_t)((int)q1 & 0xFF)) << (8 * j);
            bq |= ((uint32_t)((int)q2 & 0xFF)) << (8 * j);
        }
        u1[o] = a; u2[o] = bq;
    }
    uint8_t* wrow = Wq + (size_t)n * ((size_t)K * 2) + kt * 128;
    uint4* d = (uint4*)wrow;
    const uint4* p1 = (const uint4*)u1;
    const uint4* p2 = (const uint4*)u2;
    d[0] = p1[0]; d[1] = p1[1]; d[2] = p1[2]; d[3] = p1[3];
    d[4] = p2[0]; d[5] = p2[1]; d[6] = p2[2]; d[7] = p2[3];
}

// ---------------------------------------------------------------------------
// Batched variants for the 8 residual weight matrices rW[8][1024][1024].
// Global column index c in [0,8192): layer = c>>10, n = c&1023.
// ---------------------------------------------------------------------------
__global__ __launch_bounds__(256)
void col_absmax_rw(const float* __restrict__ rW, float* __restrict__ part) {
    int c = blockIdx.y * 256 + threadIdx.x;     // 0..8191
    int kp = blockIdx.x;                        // 0..7
    int layer = c >> 10, n = c & 1023;
    const float* W = rW + ((size_t)layer << 20);
    int k0 = kp * 128;
    float m = 0.f;
    for (int k = k0; k < k0 + 128; ++k)
        m = fmaxf(m, fabsf(W[(size_t)k * 1024 + n]));
    part[kp * 8192 + c] = m;
}

__global__ __launch_bounds__(256)
void col_scale_rw(const float* __restrict__ part, float* __restrict__ sB) {
    int c = blockIdx.x * 256 + threadIdx.x;     // 0..8191
    float m = 0.f;
#pragma unroll
    for (int kp = 0; kp < 8; ++kp) m = fmaxf(m, part[kp * 8192 + c]);
    m = fmaxf(m, 1e-30f);
    sB[c] = m * (1.f / 127.f);
}

__global__ __launch_bounds__(64)
void conv_wq_rw(const float* __restrict__ rW, const float* __restrict__ sB,
                uint8_t* __restrict__ Wq) {
    int c = blockIdx.x * 64 + threadIdx.x;      // 0..8191
    int kt = blockIdx.y;                        // 0..15
    int layer = c >> 10, n = c & 1023;
    const float* W = rW + ((size_t)layer << 20);
    float inv = 1.f / sB[c];
    uint32_t u1[16], u2[16];
#pragma unroll 4
    for (int o = 0; o < 16; ++o) {
        uint32_t a = 0, bq = 0;
#pragma unroll
        for (int j = 0; j < 4; ++j) {
            float q = W[(size_t)(kt * 64 + o * 4 + j) * 1024 + n] * inv;
            float q1 = rintf(q);
            float q2 = rintf((q - q1) * 128.f);
            a |= ((uint32_t)((int)q1 & 0xFF)) << (8 * j);
            bq |= ((uint32_t)((int)q2 & 0xFF)) << (8 * j);
        }
        u1[o] = a; u2[o] = bq;
    }
    uint8_t* wrow = Wq + ((size_t)layer << 21) + (size_t)n * 2048 + kt * 128;
    uint4* d = (uint4*)wrow;
    const uint4* p1 = (const uint4*)u1;
    const uint4* p2 = (const uint4*)u2;
    d[0] = p1[0]; d[1] = p1[1]; d[2] = p1[2]; d[3] = p1[3];
    d[4] = p2[0]; d[5] = p2[1]; d[6] = p2[2]; d[7] = p2[3];
}

// ---------------------------------------------------------------------------
// Dual-term i8 MFMA GEMM (round-11 proven core).
// KSPLIT: grid (M/256, 2), blockIdx.y = K-half; partial outputs to
// C + y*M*N; bias applied only in half 0. No XCD swizzle under KSPLIT.
// ---------------------------------------------------------------------------
template <int MODE, bool KSPLIT = false>
__global__ __launch_bounds__(512, 2)
void gemm_i8(const uint8_t* __restrict__ Aq, const uint8_t* __restrict__ Bq,
             const float* __restrict__ sA, const float* __restrict__ sB,
             const float* __restrict__ bias, float* __restrict__ C,
             int M, int N, int K) {
    __shared__ char Abuf[2][32768];   // 256 rows x 128B
    __shared__ char Bbuf[2][16384];   // 128 rows x 128B

    const int tid = threadIdx.x;
    const int lane = tid & 63;
    const int wv = tid >> 6;
    const int wr = wv >> 1;        // 0..3  (M)
    const int wc = wv & 1;         // 0..1  (N)

    int m0, n0, nt;
    size_t kbyte0;
    float* Cout;
    if constexpr (KSPLIT) {
        m0 = blockIdx.x * 256;
        n0 = 0;
        int half = K >> 1;
        nt = half >> 6;
        kbyte0 = (size_t)blockIdx.y * half * 2;
        Cout = C + (size_t)blockIdx.y * M * N;
    } else {
        int lid = blockIdx.y * gridDim.x + blockIdx.x;
        int nwg = gridDim.x * gridDim.y;
        int chunk = nwg >> 3;
        int swz = (lid & 7) * chunk + (lid >> 3);
        int nIdx = swz % gridDim.y;
        int mIdx = swz / gridDim.y;
        m0 = mIdx * 256; n0 = nIdx * 128;
        nt = K >> 6;
        kbyte0 = 0;
        Cout = C;
    }

    const size_t rowB = (size_t)K * 2;   // quantized row bytes

    int arow[4], aq[4];
#pragma unroll
    for (int i = 0; i < 4; ++i) {
        int s = i * 512 + tid;
        arow[i] = s >> 3;
        aq[i] = (s & 7) ^ (arow[i] & 7);
    }
    int brow[2], bq[2];
#pragma unroll
    for (int i = 0; i < 2; ++i) {
        int s = i * 512 + tid;
        brow[i] = s >> 3;
        bq[i] = (s & 7) ^ (brow[i] & 7);
    }

    i32x4 accP[4][4] = {};
    i32x4 accQ[4][4] = {};

#pragma unroll
    for (int i = 0; i < 4; ++i)
        gload_lds16((const char*)Aq + (size_t)(m0 + arow[i]) * rowB + kbyte0 + aq[i] * 16,
                    Abuf[0] + (i * 512 + tid) * 16);
#pragma unroll
    for (int i = 0; i < 2; ++i)
        gload_lds16((const char*)Bq + (size_t)(n0 + brow[i]) * rowB + kbyte0 + bq[i] * 16,
                    Bbuf[0] + (i * 512 + tid) * 16);
    __syncthreads();

    int p = 0;
    const int g = lane >> 4;
    const int rr = lane & 15;

    for (int kt = 0; kt < nt; ++kt) {
        if (kt + 1 < nt) {
            const size_t koff = kbyte0 + (size_t)(kt + 1) * 128;
#pragma unroll
            for (int i = 0; i < 4; ++i)
                gload_lds16((const char*)Aq + (size_t)(m0 + arow[i]) * rowB + koff + aq[i] * 16,
                            Abuf[p ^ 1] + (i * 512 + tid) * 16);
#pragma unroll
            for (int i = 0; i < 2; ++i)
                gload_lds16((const char*)Bq + (size_t)(n0 + brow[i]) * rowB + koff + bq[i] * 16,
                            Bbuf[p ^ 1] + (i * 512 + tid) * 16);
        }

        const char* Ab = Abuf[p];
        const char* Bb = Bbuf[p];

        i32x4 a1[4], b1[4];
#pragma unroll
        for (int m = 0; m < 4; ++m) {
            int rA = wr * 64 + m * 16 + rr;
            a1[m] = *(const i32x4*)(Ab + rA * 128 + ((g ^ (rA & 7)) * 16));
        }
#pragma unroll
        for (int n = 0; n < 4; ++n) {
            int rB = wc * 64 + n * 16 + rr;
            b1[n] = *(const i32x4*)(Bb + rB * 128 + ((g ^ (rB & 7)) * 16));
        }
#pragma unroll
        for (int m = 0; m < 4; ++m)
#pragma unroll
            for (int n = 0; n < 4; ++n)
                accP[m][n] = __builtin_amdgcn_mfma_i32_16x16x64_i8(a1[m], b1[n], accP[m][n], 0, 0, 0);

        {
            i32x4 b2[4];
#pragma unroll
            for (int n = 0; n < 4; ++n) {
                int rB = wc * 64 + n * 16 + rr;
                b2[n] = *(const i32x4*)(Bb + rB * 128 + (((g + 4) ^ (rB & 7)) * 16));
            }
#pragma unroll
            for (int m = 0; m < 4; ++m)
#pragma unroll
                for (int n = 0; n < 4; ++n)
                    accQ[m][n] = __builtin_amdgcn_mfma_i32_16x16x64_i8(a1[m], b2[n], accQ[m][n], 0, 0, 0);
        }
        {
            i32x4 a2[4];
#pragma unroll
            for (int m = 0; m < 4; ++m) {
                int rA = wr * 64 + m * 16 + rr;
                a2[m] = *(const i32x4*)(Ab + rA * 128 + (((g + 4) ^ (rA & 7)) * 16));
            }
#pragma unroll
            for (int m = 0; m < 4; ++m)
#pragma unroll
                for (int n = 0; n < 4; ++n)
                    accQ[m][n] = __builtin_amdgcn_mfma_i32_16x16x64_i8(a2[m], b1[n], accQ[m][n], 0, 0, 0);
        }

        __syncthreads();
        p ^= 1;
    }

    // epilogue: C/D layout col = lane&15, row = (lane>>4)*4 + j
#pragma unroll
    for (int m = 0; m < 4; ++m) {
        int rbase = m0 + wr * 64 + m * 16 + (lane >> 4) * 4;
#pragma unroll
        for (int n = 0; n < 4; ++n) {
            int c = n0 + wc * 64 + n * 16 + (lane & 15);
            float sbc = sB[c];
            float bv = bias[c];
            if (KSPLIT && blockIdx.y != 0) bv = 0.f;
#pragma unroll
            for (int j = 0; j < 4; ++j) {
                int r = rbase + j;
                float v = sA[r] * sbc *
                          ((float)accP[m][n][j] + 0.0078125f * (float)accQ[m][n][j]) + bv;
                float* cp = &Cout[(size_t)r * N + c];
                if (MODE == 0) *cp = fmaxf(v, 0.f);
                else if (MODE == 1) *cp = *cp + fmaxf(v, 0.f);
                else *cp = v;
            }
        }
    }
}

// ---------------------------------------------------------------------------
// 8-wide simultaneous block reduction: v[8] per thread -> out[8] (shared).
// ---------------------------------------------------------------------------
template <bool MAXOP>
__device__ __forceinline__ void red8(const float* v, float* out, float (*scr)[4]) {
    int lane = threadIdx.x & 63, wv = threadIdx.x >> 6, tid = threadIdx.x;
#pragma unroll
    for (int oo = 0; oo < 8; ++oo) {
        float r = v[oo];
#pragma unroll
        for (int m = 1; m < 64; m <<= 1) {
            float t = __shfl_xor(r, m);
            r = MAXOP ? fmaxf(r, t) : r + t;
        }
        if (lane == 0) scr[oo][wv] = r;
    }
    __syncthreads();
    if (tid < 8) {
        float a = scr[tid][0], b = scr[tid][1], c = scr[tid][2], d = scr[tid][3];
        out[tid] = MAXOP ? fmaxf(fmaxf(a, b), fmaxf(c, d)) : (a + b + c + d);
    }
    __syncthreads();
}

// ---------------------------------------------------------------------------
// Attention over time, 8 outputs per block. grid = 64 bs * 16 ogroups = 1024
// (4 blocks/CU for latency hiding). P=2 j-blocking (proven): thread
// (jgrp=tid>>1, kp=tid&1) owns 2 j-columns; j == tid preserved.
// fc input is split-K partials: vv = fc0 + fc1.
// ---------------------------------------------------------------------------
__global__ __launch_bounds__(256)
void attn_g8(const float* __restrict__ fc01,
             const float* __restrict__ g1, const float* __restrict__ b1,
             const float* __restrict__ Wa1, const float* __restrict__ ba1,
             const float* __restrict__ g2, const float* __restrict__ b2,
             const float* __restrict__ Wa2, const float* __restrict__ ba2,
             float* __restrict__ out) {
    __shared__ float buf[257][12];
    __shared__ float scr[8][4];
    __shared__ float sS[8], sQ[8], sO[8];

    const int R128 = 16384 * 128;
    int bs = blockIdx.x >> 4;
    int o0 = (blockIdx.x & 15) * 8;
    int tid = threadIdx.x;
    int jgrp = tid >> 1;
    int kp = tid & 1;

    float vv[8], tmp[8];
    size_t base = (size_t)(bs * 256 + tid) * 128 + o0;
    const float4* fp0 = (const float4*)(fc01 + base);
    const float4* fp1 = (const float4*)(fc01 + R128 + base);
#pragma unroll
    for (int q = 0; q < 2; ++q) {
        float4 t0 = fp0[q];
        float4 t1 = fp1[q];
        vv[4 * q] = t0.x + t1.x; vv[4 * q + 1] = t0.y + t1.y;
        vv[4 * q + 2] = t0.z + t1.z; vv[4 * q + 3] = t0.w + t1.w;
    }

#pragma unroll
    for (int oo = 0; oo < 8; ++oo) tmp[oo] = vv[oo] * vv[oo];
    red8<false>(vv, sS, scr);
    red8<false>(tmp, sQ, scr);

    float gl = g1[tid], bl = b1[tid];
#pragma unroll
    for (int oo = 0; oo < 8; ++oo) {
        float s = sS[oo], q = sQ[oo];
        float mean = s * (1.f / 256.f);
        float mu = (s + mean) * (1.f / 257.f);
        float var = (q + mean * mean) * (1.f / 257.f) - mu * mu;
        float rstd = rsqrtf(var + EPSV);
        tmp[oo] = (vv[oo] - mu) * rstd * gl + bl;
    }
#pragma unroll
    for (int q = 0; q < 2; ++q)
        *(float4*)&buf[tid][4 * q] = *(float4*)&tmp[4 * q];
    if (tid < 8) {
        int oo = tid;
        float s = sS[oo], q = sQ[oo];
        float mean = s * (1.f / 256.f);
        float mu = (s + mean) * (1.f / 257.f);
        float var = (q + mean * mean) * (1.f / 257.f) - mu * mu;
        float rstd = rsqrtf(var + EPSV);
        buf[256][oo] = (mean - mu) * rstd * g1[256] + b1[256];
    }
    __syncthreads();

    // GEMV1: acc1[oo][jj] over k ≡ kp (mod 2)
    float acc1[8][2] = {};
#pragma unroll 2
    for (int i = 0; i < 128; ++i) {
        int k = 2 * i + kp;
        float2 wv2 = *(const float2*)&Wa1[(size_t)k * 256 + jgrp * 2];
        float4 t0 = *(const float4*)&buf[k][0];
        float4 t1 = *(const float4*)&buf[k][4];
        float bv[8] = { t0.x, t0.y, t0.z, t0.w, t1.x, t1.y, t1.z, t1.w };
#pragma unroll
        for (int oo = 0; oo < 8; ++oo) {
            acc1[oo][0] = fmaf(bv[oo], wv2.x, acc1[oo][0]);
            acc1[oo][1] = fmaf(bv[oo], wv2.y, acc1[oo][1]);
        }
    }
    if (kp == 0) {   // k = 256 tail
        float2 wv2 = *(const float2*)&Wa1[(size_t)256 * 256 + jgrp * 2];
#pragma unroll
        for (int oo = 0; oo < 8; ++oo) {
            float bv = buf[256][oo];
            acc1[oo][0] = fmaf(bv, wv2.x, acc1[oo][0]);
            acc1[oo][1] = fmaf(bv, wv2.y, acc1[oo][1]);
        }
    }
    float a_[8];
#pragma unroll
    for (int oo = 0; oo < 8; ++oo) {
        float p0 = acc1[oo][0] + __shfl_xor(acc1[oo][0], 1);
        float p1 = acc1[oo][1] + __shfl_xor(acc1[oo][1], 1);
        a_[oo] = kp ? p1 : p0;
    }
    float bb = ba1[tid];
#pragma unroll
    for (int oo = 0; oo < 8; ++oo) a_[oo] = fmaxf(a_[oo] + bb, 0.f);

#pragma unroll
    for (int oo = 0; oo < 8; ++oo) tmp[oo] = a_[oo] * a_[oo];
    red8<false>(a_, sS, scr);
    red8<false>(tmp, sQ, scr);

    float g2l = g2[tid], b2l = b2[tid];
#pragma unroll
    for (int oo = 0; oo < 8; ++oo) {
        float mu2 = sS[oo] * (1.f / 256.f);
        float rstd2 = rsqrtf(sQ[oo] * (1.f / 256.f) - mu2 * mu2 + EPSV);
        tmp[oo] = (a_[oo] - mu2) * rstd2 * g2l + b2l;
    }
#pragma unroll
    for (int q = 0; q < 2; ++q)
        *(float4*)&buf[tid][4 * q] = *(float4*)&tmp[4 * q];
    __syncthreads();

    // GEMV2
    float acc2[8][2] = {};
#pragma unroll 2
    for (int i = 0; i < 128; ++i) {
        int k = 2 * i + kp;
        float2 wv2 = *(const float2*)&Wa2[(size_t)k * 256 + jgrp * 2];
        float4 t0 = *(const float4*)&buf[k][0];
        float4 t1 = *(const float4*)&buf[k][4];
        float bv[8] = { t0.x, t0.y, t0.z, t0.w, t1.x, t1.y, t1.z, t1.w };
#pragma unroll
        for (int oo = 0; oo < 8; ++oo) {
            acc2[oo][0] = fmaf(bv[oo], wv2.x, acc2[oo][0]);
            acc2[oo][1] = fmaf(bv[oo], wv2.y, acc2[oo][1]);
        }
    }
    float w_[8];
#pragma unroll
    for (int oo = 0; oo < 8; ++oo) {
        float p0 = acc2[oo][0] + __shfl_xor(acc2[oo][0], 1);
        float p1 = acc2[oo][1] + __shfl_xor(acc2[oo][1], 1);
        w_[oo] = kp ? p1 : p0;
    }
    float bb2 = ba2[tid];
#pragma unroll
    for (int oo = 0; oo < 8; ++oo) w_[oo] += bb2;

    red8<true>(w_, sO, scr);
    float e_[8];
#pragma unroll
    for (int oo = 0; oo < 8; ++oo) e_[oo] = __expf(w_[oo] - sO[oo]);
    red8<false>(e_, sS, scr);
#pragma unroll
    for (int oo = 0; oo < 8; ++oo) tmp[oo] = vv[oo] * e_[oo] / sS[oo];
    red8<false>(tmp, sQ, scr);
    if (tid < 8) out[bs * 128 + o0 + tid] = sQ[tid];
}

// ---------------------------------------------------------------------------
// Launch
// ---------------------------------------------------------------------------
extern "C" void kernel_launch(void* const* d_in, const int* in_sizes, int n_in,
                              void* d_out, int out_size, void* d_ws, size_t ws_size,
                              hipStream_t stream) {
    const float* x      = (const float*)d_in[0];
    const float* ln0_g  = (const float*)d_in[1];
    const float* ln0_b  = (const float*)d_in[2];
    const float* W0     = (const float*)d_in[3];
    const float* b0     = (const float*)d_in[4];
    const float* rln_g  = (const float*)d_in[5];
    const float* rln_b  = (const float*)d_in[6];
    const float* rW     = (const float*)d_in[7];
    const float* rb     = (const float*)d_in[8];
    const float* lnf_g  = (const float*)d_in[9];
    const float* lnf_b  = (const float*)d_in[10];
    const float* Wf     = (const float*)d_in[11];
    const float* bf_    = (const float*)d_in[12];
    const float* ln1_g  = (const float*)d_in[13];
    const float* ln1_b  = (const float*)d_in[14];
    const float* Wa1    = (const float*)d_in[15];
    const float* ba1    = (const float*)d_in[16];
    const float* ln2_g  = (const float*)d_in[17];
    const float* ln2_b  = (const float*)d_in[18];
    const float* Wa2    = (const float*)d_in[19];
    const float* ba2    = (const float*)d_in[20];
    float* out = (float*)d_out;

    const int R = 64 * 256;   // 16384 rows
    float*    h     = (float*)d_ws;                        // 64 MB
    uint8_t*  Aq    = (uint8_t*)(h + (size_t)R * 1024);    // 32 MB
    float*    fc01  = (float*)(Aq + (size_t)R * 2048);     // 2*R*128 f32 (16 MB)
    uint8_t*  Wq0   = (uint8_t*)(fc01 + (size_t)2 * R * 128);      // 1 MB
    uint8_t*  WqR   = Wq0 + (size_t)1024 * 1024;                   // 16 MB
    uint8_t*  Wqf   = WqR + (size_t)8 * 1024 * 2048;               // 256 KB
    float*    sA    = (float*)(Wqf + (size_t)128 * 2048);          // R f32
    float*    sB0   = sA + R;                                      // 1024
    float*    sBR   = sB0 + 1024;                                  // 8192
    float*    sBf   = sBR + 8192;                                  // 128
    float*    part  = sBf + 128;                                   // 8*8192

    // ---- weight prep (all hoisted; 9 launches) ----
    col_absmax<<<dim3(8, 4), 256, 0, stream>>>(W0, part, 512, 1024);
    col_scale<<<4, 256, 0, stream>>>(part, sB0, 1024);
    conv_wq<<<dim3(16, 8), 64, 0, stream>>>(W0, sB0, Wq0, 512, 1024);

    col_absmax_rw<<<dim3(8, 32), 256, 0, stream>>>(rW, part);
    col_scale_rw<<<32, 256, 0, stream>>>(part, sBR);
    conv_wq_rw<<<dim3(128, 16), 64, 0, stream>>>(rW, sBR, WqR);

    col_absmax<<<dim3(8, 1), 256, 0, stream>>>(Wf, part, 1024, 128);
    col_scale<<<1, 256, 0, stream>>>(part, sBf, 128);
    conv_wq<<<dim3(2, 16), 64, 0, stream>>>(Wf, sBf, Wqf, 1024, 128);

    // ---- trunk ----
    ln_quant<<<R, 256, 0, stream>>>(x, ln0_g, ln0_b, Aq, sA, 512);
    gemm_i8<0><<<dim3(64, 8), 512, 0, stream>>>(Aq, Wq0, sA, sB0, b0, h, R, 1024, 512);

    for (int i = 0; i < 8; ++i) {
        ln_quant<<<R, 256, 0, stream>>>(h, rln_g + i * 1024, rln_b + i * 1024, Aq, sA, 1024);
        gemm_i8<1><<<dim3(64, 8), 512, 0, stream>>>(
            Aq, WqR + ((size_t)i << 21), sA, sBR + i * 1024, rb + i * 1024, h, R, 1024, 1024);
    }

    // head: split-K=2, one launch, partials to fc01[0], fc01[1]
    ln_quant<<<R, 256, 0, stream>>>(h, lnf_g, lnf_b, Aq, sA, 1024);
    gemm_i8<2, true><<<dim3(64, 2), 512, 0, stream>>>(Aq, Wqf, sA, sBf, bf_, fc01, R, 128, 1024);

    // fused attention + weighted sum (8 outputs per block, 1024 blocks)
    attn_g8<<<64 * 16, 256, 0, stream>>>(fc01, ln1_g, ln1_b, Wa1, ba1,
                                         ln2_g, ln2_b, Wa2, ba2, out);
}